// Round 1
// baseline (1297.192 us; speedup 1.0000x reference)
//
#include <hip/hip_runtime.h>
#include <cstddef>

#define NROWS 16384
#define NE    8192
#define DD    256
#define TM    128
#define TN    128
#define BK    16
#define NCH   8
#define CHW   (NE / NCH)   // 1024 cols per chunk
#define NBLK  ((NROWS / TM) * NCH)          // 1024 blocks
#define SLOTS_PER_BLK ((size_t)33554432 / NBLK)  // 32768 vf4 slots per block

typedef unsigned long long u64;
typedef float vf4 __attribute__((ext_vector_type(4)));
typedef float vf2 __attribute__((ext_vector_type(2)));

#define OH_TOT ((size_t)NROWS * NE)           // 134217728 floats
#define OH_VEC ((OH_TOT - 4) / 4)             // 33554431 aligned vf4 slots

// ---------------------------------------------------------------------------
// k_rowsq: zsq[n] = sum(z[n,:]^2) in numpy pairwise order (256 = 128+128,
// each 128-block via 8 strided accumulators r[j] += x[8i+j]^2, combined
// pairwise). float4 loads (same add order as scalar). Also inits best[],
// counts.
// ---------------------------------------------------------------------------
__global__ __launch_bounds__(256) void k_rowsq(
    const float* __restrict__ z, const float* __restrict__ emb,
    float* __restrict__ zsq, float* __restrict__ esq,
    u64* __restrict__ best, int* __restrict__ counts)
{
  const int g = blockIdx.x * 256 + threadIdx.x;   // 0 .. 24575
  if (g < NE) counts[g] = 0;
  if (g < NROWS) best[g] = ~0ull;

  const float* row;
  float* outp;
  if (g < NROWS) { row = z + (size_t)g * DD;            outp = zsq + g; }
  else           { row = emb + (size_t)(g - NROWS) * DD; outp = esq + (g - NROWS); }

  float half_s[2];
#pragma unroll
  for (int h = 0; h < 2; ++h) {
    const float* p = row + h * 128;
    float r[8];
    {
      const float4 v0 = *(const float4*)(p);
      const float4 v1 = *(const float4*)(p + 4);
      const float xs[8] = {v0.x, v0.y, v0.z, v0.w, v1.x, v1.y, v1.z, v1.w};
#pragma unroll
      for (int j = 0; j < 8; ++j) {
        float sq = xs[j] * xs[j];
        asm volatile("" : "+v"(sq));   // block FMA contraction: np rounds x*x first
        r[j] = sq;
      }
    }
    for (int i = 8; i < 128; i += 8) {
      const float4 v0 = *(const float4*)(p + i);
      const float4 v1 = *(const float4*)(p + i + 4);
      const float xs[8] = {v0.x, v0.y, v0.z, v0.w, v1.x, v1.y, v1.z, v1.w};
#pragma unroll
      for (int j = 0; j < 8; ++j) {
        float sq = xs[j] * xs[j];
        asm volatile("" : "+v"(sq));
        r[j] = r[j] + sq;
      }
    }
    half_s[h] = ((r[0] + r[1]) + (r[2] + r[3])) + ((r[4] + r[5]) + (r[6] + r[7]));
  }
  *outp = half_s[0] + half_s[1];
}

// ---------------------------------------------------------------------------
// k_argmin v8: same arithmetic as v7 (ascending-k v_pk_fma_f32 chains,
// s1 = fl(zsq+esq), dv = fl(s1 - 2*dot), u64-packed atomicMin argmin,
// fused one-hot zero-fill) but reshaped for occupancy:
//   TM 256->128, per-thread tile 16x8 -> 8x8 (acc 128 -> 64 VGPRs),
//   grid 512 -> 1024 blocks (4 blocks/CU), LDS 48 KB -> 32 KB,
//   waves_per_eu 2 -> 4.  Per-output rounding sequence is unchanged, so
// argmin decisions stay bit-identical to v7 / the reference.
// ---------------------------------------------------------------------------
__global__ __launch_bounds__(256)
__attribute__((amdgpu_waves_per_eu(4, 4)))
void k_argmin(
    const float* __restrict__ z, const float* __restrict__ emb,
    const float* __restrict__ zsq, const float* __restrict__ esq,
    u64* __restrict__ best, float* __restrict__ ohbase)
{
  __shared__ float As[2][BK][TM];       // 16 KB
  __shared__ float Bs[2][BK][TN];       // 16 KB

  const int tid = threadIdx.x;
  const int tx = tid & 15;
  const int ty = tid >> 4;
  const int tx4 = tx * 4;
  const int ty4 = ty * 4;
  const int R0 = blockIdx.x * TM;
  const int C0 = blockIdx.y * CHW;

  const int lcol = tid & 127;           // staging index: A row / B col
  const int lk8  = (tid >> 7) * 8;      // staging k-offset (0 or 8)

  const float* zrow = z + (size_t)(R0 + lcol) * DD + lk8;

  // one-hot zero-fill: flat block id owns vf4 slots [b*32768,(b+1)*32768)
  const int bflat = blockIdx.y * (NROWS / TM) + blockIdx.x;   // 0..1023
  size_t zt = (size_t)bflat * SLOTS_PER_BLK + tid;            // step 256, x128
  float* zp = ohbase + 2;                                     // 16B-aligned
  const vf4 zzero = {0.0f, 0.0f, 0.0f, 0.0f};
  if (bflat == 0 && tid == 0) { ohbase[0] = 0.0f; ohbase[1] = 0.0f; }
  if (bflat == NBLK - 1 && tid == 0) {
    ohbase[OH_TOT - 2] = 0.0f; ohbase[OH_TOT - 1] = 0.0f;
  }

  u64 bp[8];
#pragma unroll
  for (int i = 0; i < 8; ++i) bp[i] = ~0ull;

#define STAGE(B_, K_)                                                     \
  {                                                                       \
    _Pragma("unroll")                                                     \
    for (int h = 0; h < 2; ++h) {                                         \
      const float4 v = *(const float4*)(zrow + (K_) + 4 * h);             \
      As[B_][lk8 + 4 * h + 0][lcol] = v.x;                                \
      As[B_][lk8 + 4 * h + 1][lcol] = v.y;                                \
      As[B_][lk8 + 4 * h + 2][lcol] = v.z;                                \
      As[B_][lk8 + 4 * h + 3][lcol] = v.w;                                \
    }                                                                     \
    _Pragma("unroll")                                                     \
    for (int h = 0; h < 2; ++h) {                                         \
      const float4 v = *(const float4*)(ecol + (K_) + 4 * h);             \
      Bs[B_][lk8 + 4 * h + 0][lcol] = v.x;                                \
      Bs[B_][lk8 + 4 * h + 1][lcol] = v.y;                                \
      Bs[B_][lk8 + 4 * h + 2][lcol] = v.z;                                \
      Bs[B_][lk8 + 4 * h + 3][lcol] = v.w;                                \
    }                                                                     \
    if (zt < OH_VEC) __builtin_nontemporal_store(zzero, (vf4*)(zp + 4 * zt)); \
    zt += 256;                                                            \
  }

#define COMPUTE(B_)                                                       \
  _Pragma("unroll 2")                                                     \
  for (int kk = 0; kk < BK; ++kk) {                                       \
    const float4 a0 = *(const float4*)(&As[B_][kk][ty4]);                 \
    const float4 a1 = *(const float4*)(&As[B_][kk][ty4 + 64]);            \
    const float4 b0 = *(const float4*)(&Bs[B_][kk][tx4]);                 \
    const float4 b1 = *(const float4*)(&Bs[B_][kk][tx4 + 64]);            \
    const float av[8] = {a0.x, a0.y, a0.z, a0.w, a1.x, a1.y, a1.z, a1.w}; \
    const vf2 b2[4] = {{b0.x, b0.y}, {b0.z, b0.w},                        \
                       {b1.x, b1.y}, {b1.z, b1.w}};                       \
    _Pragma("unroll")                                                     \
    for (int i = 0; i < 8; ++i) {                                         \
      const vf2 a2v = {av[i], av[i]};                                     \
      _Pragma("unroll")                                                   \
      for (int j = 0; j < 4; ++j)                                         \
        acc[i][j] = __builtin_elementwise_fma(a2v, b2[j], acc[i][j]);     \
    }                                                                     \
  }

  for (int t = 0; t < CHW; t += TN) {
    const int Cb = C0 + t;
    const float* ecol = emb + (size_t)(Cb + lcol) * DD + lk8;

    vf2 acc[8][4];   // [i][j2]: j2=0,1 -> cols tx4+0..3 ; j2=2,3 -> tx4+64..67
#pragma unroll
    for (int i = 0; i < 8; ++i)
#pragma unroll
      for (int j = 0; j < 4; ++j) acc[i][j] = (vf2){0.0f, 0.0f};

    STAGE(0, 0);
    __syncthreads();
    for (int c = 0; c < 16; c += 2) {
      if (c + 1 < 16) STAGE(1, (c + 1) * BK);
      COMPUTE(0);
      __syncthreads();
      if (c + 2 < 16) STAGE(0, (c + 2) * BK);
      COMPUTE(1);
      __syncthreads();
    }

#pragma unroll
    for (int j = 0; j < 8; ++j) {
      const int col = Cb + tx4 + ((j < 4) ? j : 64 + j - 4);
      const float ev = esq[col];
#pragma unroll
      for (int i = 0; i < 8; ++i) {
        const float zri = zsq[R0 + (i >> 2) * 64 + ty4 + (i & 3)];
        const float aij = acc[i][j >> 1][j & 1];
        const float s1 = zri + ev;                // fl(zsq+esq), matches np
        const float dv = s1 - 2.0f * aij;         // fl(s1 - 2*dot); 2*dot exact
        const u64 p = ((u64)__float_as_uint(dv) << 32) | (unsigned)col;
        if (p < bp[i]) bp[i] = p;
      }
    }
  }

#pragma unroll
  for (int i = 0; i < 8; ++i) {
#pragma unroll
    for (int off = 8; off > 0; off >>= 1) {
      const u64 o = __shfl_xor(bp[i], off, 16);
      if (o < bp[i]) bp[i] = o;
    }
  }
  if (tx == 0) {
#pragma unroll
    for (int i = 0; i < 8; ++i) {
      const int r = R0 + (i >> 2) * 64 + ty4 + (i & 3);
      atomicMin(&best[r], bp[i]);
    }
  }
}

// ---------------------------------------------------------------------------
// k_gather2: 4 rows per block. z_q gather, one-hot 1.0 scatter (zeros were
// laid down by k_argmin), float(index), counts, per-block loss partial.
// ---------------------------------------------------------------------------
__global__ __launch_bounds__(256) void k_gather2(
    const float* __restrict__ z, const float* __restrict__ emb,
    const u64* __restrict__ best,
    float* __restrict__ out_zq, float* __restrict__ out_onehot,
    float* __restrict__ out_idx, float* __restrict__ partials,
    int* __restrict__ counts)
{
  __shared__ float sred[256];
  const int row = blockIdx.x * 4 + (threadIdx.x >> 6);
  const int lane = threadIdx.x & 63;
  const int idx = (int)(unsigned)(best[row] & 0xffffffffull);
  const int k0 = lane * 4;

  const float4 e  = *(const float4*)(emb + (size_t)idx * DD + k0);
  const float4 zv = *(const float4*)(z + (size_t)row * DD + k0);
  *(float4*)(out_zq + (size_t)row * DD + k0) = e;

  const float dx = e.x - zv.x, dy = e.y - zv.y, dz = e.z - zv.z, dw = e.w - zv.w;
  sred[threadIdx.x] = dx * dx + dy * dy + dz * dz + dw * dw;

  if (lane == 0) {
    out_idx[row] = (float)idx;
    out_onehot[(size_t)row * NE + idx] = 1.0f;
    atomicAdd(&counts[idx], 1);
  }
  __syncthreads();
  for (int s = 128; s > 0; s >>= 1) {
    if (threadIdx.x < s) sred[threadIdx.x] += sred[threadIdx.x + s];
    __syncthreads();
  }
  if (threadIdx.x == 0) partials[blockIdx.x] = sred[0];
}

// ---------------------------------------------------------------------------
// k_final: loss = 1.25 * sum(partials) / (N*D); perplexity from counts.
// ---------------------------------------------------------------------------
__global__ __launch_bounds__(256) void k_final(
    const int* __restrict__ counts, const float* __restrict__ partials,
    float* __restrict__ out_loss, float* __restrict__ out_perp)
{
  __shared__ float sred[256];
  __shared__ float sl[256];
  float le = 0.0f;
  for (int e = threadIdx.x; e < NE; e += 256) {
    const float p = (float)counts[e] * (1.0f / 16384.0f);
    le += p * logf(p + 1e-10f);
  }
  float ll = 0.0f;
  for (int b = threadIdx.x; b < NROWS / 4; b += 256) ll += partials[b];
  sred[threadIdx.x] = le;
  sl[threadIdx.x] = ll;
  __syncthreads();
  for (int s = 128; s > 0; s >>= 1) {
    if (threadIdx.x < s) {
      sred[threadIdx.x] += sred[threadIdx.x + s];
      sl[threadIdx.x] += sl[threadIdx.x + s];
    }
    __syncthreads();
  }
  if (threadIdx.x == 0) {
    *out_perp = expf(-sred[0]);
    *out_loss = sl[0] * (1.25f / 4194304.0f);  // (1+beta) * sum / (N*D)
  }
}

// ---------------------------------------------------------------------------
// Output layout (float32, concatenated in reference return order):
//   [0]                loss                       (1)
//   [1 .. 4194304]     z_q_st                     (16384*256)
//   [4194305]          perplexity                 (1)
//   [4194306 ..]       min_encodings one-hot      (16384*8192)
//   [138412034 ..]     min_encoding_indices       (16384, written as float)
// ---------------------------------------------------------------------------
extern "C" void kernel_launch(void* const* d_in, const int* in_sizes, int n_in,
                              void* d_out, int out_size, void* d_ws, size_t ws_size,
                              hipStream_t stream) {
  const float* z   = (const float*)d_in[0];
  const float* emb = (const float*)d_in[1];

  float* out        = (float*)d_out;
  float* out_loss   = out;
  float* out_zq     = out + 1;
  float* out_perp   = out + 4194305;
  float* out_onehot = out + 4194306;
  float* out_idx    = out + 138412034;

  float* zsq      = (float*)d_ws;            // 16384 f
  float* esq      = zsq + NROWS;             // 8192 f
  u64*   best     = (u64*)(esq + NE);        // 16384 u64 (8B-aligned: offset 96 KB)
  int*   counts   = (int*)(best + NROWS);    // 8192 int
  float* partials = (float*)(counts + NE);   // 4096 f

  k_rowsq<<<96, 256, 0, stream>>>(z, emb, zsq, esq, best, counts);
  k_argmin<<<dim3(NROWS / TM, NCH), 256, 0, stream>>>(z, emb, zsq, esq, best,
                                                      out_onehot);
  k_gather2<<<NROWS / 4, 256, 0, stream>>>(z, emb, best, out_zq, out_onehot,
                                           out_idx, partials, counts);
  k_final<<<1, 256, 0, stream>>>(counts, partials, out_loss, out_perp);
}

// Round 3
// 1287.343 us; speedup vs baseline: 1.0077x; 1.0077x over previous
//
#include <hip/hip_runtime.h>
#include <cstddef>

#define NROWS 16384
#define NE    8192
#define DD    256
#define TM    128
#define TN    128
#define BK    16
#define NCH   8
#define CHW   (NE / NCH)   // 1024 cols per chunk
#define NBLK  ((NROWS / TM) * NCH)          // 1024 blocks
#define SLOTS_PER_BLK ((size_t)33554432 / NBLK)  // 32768 vf4 slots per block

typedef unsigned long long u64;
typedef float vf4 __attribute__((ext_vector_type(4)));
typedef float vf2 __attribute__((ext_vector_type(2)));

#define OH_TOT ((size_t)NROWS * NE)           // 134217728 floats
#define OH_VEC ((OH_TOT - 4) / 4)             // 33554431 aligned vf4 slots

// ---------------------------------------------------------------------------
// k_rowsq: zsq[n] = sum(z[n,:]^2) in numpy pairwise order (256 = 128+128,
// each 128-block via 8 strided accumulators r[j] += x[8i+j]^2, combined
// pairwise). float4 loads (same add order as scalar). Also inits best[],
// counts.
// ---------------------------------------------------------------------------
__global__ __launch_bounds__(256) void k_rowsq(
    const float* __restrict__ z, const float* __restrict__ emb,
    float* __restrict__ zsq, float* __restrict__ esq,
    u64* __restrict__ best, int* __restrict__ counts)
{
  const int g = blockIdx.x * 256 + threadIdx.x;   // 0 .. 24575
  if (g < NE) counts[g] = 0;
  if (g < NROWS) best[g] = ~0ull;

  const float* row;
  float* outp;
  if (g < NROWS) { row = z + (size_t)g * DD;            outp = zsq + g; }
  else           { row = emb + (size_t)(g - NROWS) * DD; outp = esq + (g - NROWS); }

  float half_s[2];
#pragma unroll
  for (int h = 0; h < 2; ++h) {
    const float* p = row + h * 128;
    float r[8];
    {
      const float4 v0 = *(const float4*)(p);
      const float4 v1 = *(const float4*)(p + 4);
      const float xs[8] = {v0.x, v0.y, v0.z, v0.w, v1.x, v1.y, v1.z, v1.w};
#pragma unroll
      for (int j = 0; j < 8; ++j) {
        float sq = xs[j] * xs[j];
        asm volatile("" : "+v"(sq));   // block FMA contraction: np rounds x*x first
        r[j] = sq;
      }
    }
    for (int i = 8; i < 128; i += 8) {
      const float4 v0 = *(const float4*)(p + i);
      const float4 v1 = *(const float4*)(p + i + 4);
      const float xs[8] = {v0.x, v0.y, v0.z, v0.w, v1.x, v1.y, v1.z, v1.w};
#pragma unroll
      for (int j = 0; j < 8; ++j) {
        float sq = xs[j] * xs[j];
        asm volatile("" : "+v"(sq));
        r[j] = r[j] + sq;
      }
    }
    half_s[h] = ((r[0] + r[1]) + (r[2] + r[3])) + ((r[4] + r[5]) + (r[6] + r[7]));
  }
  *outp = half_s[0] + half_s[1];
}

// ---------------------------------------------------------------------------
// pkfma_lo/hi: v_pk_fma_f32 (VOP3P, all sources are 64-bit VGPR PAIRS).
// op_sel bit0 / op_sel_hi bit0 select which half of the src0 pair feeds the
// low / high result -> hardware broadcast of one scalar from a pair, no
// v_mov.  lo: both results use pair.lo; hi: both use pair.hi.
// Each half computes a single IEEE fp32 FMA (a*b.half + c.half), identical
// rounding to the scalar chain -> argmin decisions bit-identical.
// ---------------------------------------------------------------------------
__device__ __forceinline__ void pkfma_lo(vf2& c, vf2 a, vf2 b) {
  asm("v_pk_fma_f32 %0, %1, %2, %0 op_sel:[0,0,0] op_sel_hi:[0,1,1]"
      : "+v"(c) : "v"(a), "v"(b));
}
__device__ __forceinline__ void pkfma_hi(vf2& c, vf2 a, vf2 b) {
  asm("v_pk_fma_f32 %0, %1, %2, %0 op_sel:[1,0,0] op_sel_hi:[1,1,1]"
      : "+v"(c) : "v"(a), "v"(b));
}

// ---------------------------------------------------------------------------
// k_argmin v10: same tiling/occupancy as v8 (TM=128, 8x8 tile, 4 blocks/CU,
// 32 KB LDS). Changes vs v8:
//  - inner product via inline-asm v_pk_fma_f32 with op_sel half-broadcast of
//    the A pair (removes compiler-emitted v_mov pair-building),
//  - kk loop fully unrolled so every ds_read_b128 address is base+immediate
//    (removes per-kk address VALU),
//  - s_setprio(1) around each FMA cluster (4 blocks/CU -> phase diversity).
// Per-(row,col) arithmetic sequence unchanged -> argmin bit-identical.
// ---------------------------------------------------------------------------
__global__ __launch_bounds__(256)
__attribute__((amdgpu_waves_per_eu(4, 4)))
void k_argmin(
    const float* __restrict__ z, const float* __restrict__ emb,
    const float* __restrict__ zsq, const float* __restrict__ esq,
    u64* __restrict__ best, float* __restrict__ ohbase)
{
  __shared__ float As[2][BK][TM];       // 16 KB
  __shared__ float Bs[2][BK][TN];       // 16 KB

  const int tid = threadIdx.x;
  const int tx = tid & 15;
  const int ty = tid >> 4;
  const int tx4 = tx * 4;
  const int ty4 = ty * 4;
  const int R0 = blockIdx.x * TM;
  const int C0 = blockIdx.y * CHW;

  const int lcol = tid & 127;           // staging index: A row / B col
  const int lk8  = (tid >> 7) * 8;      // staging k-offset (0 or 8)

  const float* zrow = z + (size_t)(R0 + lcol) * DD + lk8;

  // one-hot zero-fill: flat block id owns vf4 slots [b*32768,(b+1)*32768)
  const int bflat = blockIdx.y * (NROWS / TM) + blockIdx.x;   // 0..1023
  size_t zt = (size_t)bflat * SLOTS_PER_BLK + tid;            // step 256, x128
  float* zp = ohbase + 2;                                     // 16B-aligned
  const vf4 zzero = {0.0f, 0.0f, 0.0f, 0.0f};
  if (bflat == 0 && tid == 0) { ohbase[0] = 0.0f; ohbase[1] = 0.0f; }
  if (bflat == NBLK - 1 && tid == 0) {
    ohbase[OH_TOT - 2] = 0.0f; ohbase[OH_TOT - 1] = 0.0f;
  }

  u64 bp[8];
#pragma unroll
  for (int i = 0; i < 8; ++i) bp[i] = ~0ull;

#define STAGE(B_, K_)                                                     \
  {                                                                       \
    _Pragma("unroll")                                                     \
    for (int h = 0; h < 2; ++h) {                                         \
      const float4 v = *(const float4*)(zrow + (K_) + 4 * h);             \
      As[B_][lk8 + 4 * h + 0][lcol] = v.x;                                \
      As[B_][lk8 + 4 * h + 1][lcol] = v.y;                                \
      As[B_][lk8 + 4 * h + 2][lcol] = v.z;                                \
      As[B_][lk8 + 4 * h + 3][lcol] = v.w;                                \
    }                                                                     \
    _Pragma("unroll")                                                     \
    for (int h = 0; h < 2; ++h) {                                         \
      const float4 v = *(const float4*)(ecol + (K_) + 4 * h);             \
      Bs[B_][lk8 + 4 * h + 0][lcol] = v.x;                                \
      Bs[B_][lk8 + 4 * h + 1][lcol] = v.y;                                \
      Bs[B_][lk8 + 4 * h + 2][lcol] = v.z;                                \
      Bs[B_][lk8 + 4 * h + 3][lcol] = v.w;                                \
    }                                                                     \
    if (zt < OH_VEC) __builtin_nontemporal_store(zzero, (vf4*)(zp + 4 * zt)); \
    zt += 256;                                                            \
  }

#define COMPUTE(B_)                                                       \
  {                                                                       \
    __builtin_amdgcn_s_setprio(1);                                        \
    _Pragma("unroll")                                                     \
    for (int kk = 0; kk < BK; ++kk) {                                     \
      const vf4 a0 = *(const vf4*)(&As[B_][kk][ty4]);                     \
      const vf4 a1 = *(const vf4*)(&As[B_][kk][ty4 + 64]);                \
      const vf4 b0 = *(const vf4*)(&Bs[B_][kk][tx4]);                     \
      const vf4 b1 = *(const vf4*)(&Bs[B_][kk][tx4 + 64]);                \
      const vf2 ap[4] = {__builtin_shufflevector(a0, a0, 0, 1),           \
                         __builtin_shufflevector(a0, a0, 2, 3),           \
                         __builtin_shufflevector(a1, a1, 0, 1),           \
                         __builtin_shufflevector(a1, a1, 2, 3)};          \
      const vf2 bb[4] = {__builtin_shufflevector(b0, b0, 0, 1),           \
                         __builtin_shufflevector(b0, b0, 2, 3),           \
                         __builtin_shufflevector(b1, b1, 0, 1),           \
                         __builtin_shufflevector(b1, b1, 2, 3)};          \
      _Pragma("unroll")                                                   \
      for (int ip = 0; ip < 4; ++ip) {                                    \
        _Pragma("unroll")                                                 \
        for (int j = 0; j < 4; ++j) pkfma_lo(acc[2 * ip][j], ap[ip], bb[j]); \
        _Pragma("unroll")                                                 \
        for (int j = 0; j < 4; ++j) pkfma_hi(acc[2 * ip + 1][j], ap[ip], bb[j]); \
      }                                                                   \
    }                                                                     \
    __builtin_amdgcn_s_setprio(0);                                        \
  }

  for (int t = 0; t < CHW; t += TN) {
    const int Cb = C0 + t;
    const float* ecol = emb + (size_t)(Cb + lcol) * DD + lk8;

    vf2 acc[8][4];   // [i][j2]: j2=0,1 -> cols tx4+0..3 ; j2=2,3 -> tx4+64..67
#pragma unroll
    for (int i = 0; i < 8; ++i)
#pragma unroll
      for (int j = 0; j < 4; ++j) acc[i][j] = (vf2){0.0f, 0.0f};

    STAGE(0, 0);
    __syncthreads();
    for (int c = 0; c < 16; c += 2) {
      if (c + 1 < 16) STAGE(1, (c + 1) * BK);
      COMPUTE(0);
      __syncthreads();
      if (c + 2 < 16) STAGE(0, (c + 2) * BK);
      COMPUTE(1);
      __syncthreads();
    }

#pragma unroll
    for (int j = 0; j < 8; ++j) {
      const int col = Cb + tx4 + ((j < 4) ? j : 64 + j - 4);
      const float ev = esq[col];
#pragma unroll
      for (int i = 0; i < 8; ++i) {
        const float zri = zsq[R0 + (i >> 2) * 64 + ty4 + (i & 3)];
        const float aij = acc[i][j >> 1][j & 1];
        const float s1 = zri + ev;                // fl(zsq+esq), matches np
        const float dv = s1 - 2.0f * aij;         // fl(s1 - 2*dot); 2*dot exact
        const u64 p = ((u64)__float_as_uint(dv) << 32) | (unsigned)col;
        if (p < bp[i]) bp[i] = p;
      }
    }
  }

#pragma unroll
  for (int i = 0; i < 8; ++i) {
#pragma unroll
    for (int off = 8; off > 0; off >>= 1) {
      const u64 o = __shfl_xor(bp[i], off, 16);
      if (o < bp[i]) bp[i] = o;
    }
  }
  if (tx == 0) {
#pragma unroll
    for (int i = 0; i < 8; ++i) {
      const int r = R0 + (i >> 2) * 64 + ty4 + (i & 3);
      atomicMin(&best[r], bp[i]);
    }
  }
}

// ---------------------------------------------------------------------------
// k_gather2: 4 rows per block. z_q gather, one-hot 1.0 scatter (zeros were
// laid down by k_argmin), float(index), counts, per-block loss partial.
// ---------------------------------------------------------------------------
__global__ __launch_bounds__(256) void k_gather2(
    const float* __restrict__ z, const float* __restrict__ emb,
    const u64* __restrict__ best,
    float* __restrict__ out_zq, float* __restrict__ out_onehot,
    float* __restrict__ out_idx, float* __restrict__ partials,
    int* __restrict__ counts)
{
  __shared__ float sred[256];
  const int row = blockIdx.x * 4 + (threadIdx.x >> 6);
  const int lane = threadIdx.x & 63;
  const int idx = (int)(unsigned)(best[row] & 0xffffffffull);
  const int k0 = lane * 4;

  const float4 e  = *(const float4*)(emb + (size_t)idx * DD + k0);
  const float4 zv = *(const float4*)(z + (size_t)row * DD + k0);
  *(float4*)(out_zq + (size_t)row * DD + k0) = e;

  const float dx = e.x - zv.x, dy = e.y - zv.y, dz = e.z - zv.z, dw = e.w - zv.w;
  sred[threadIdx.x] = dx * dx + dy * dy + dz * dz + dw * dw;

  if (lane == 0) {
    out_idx[row] = (float)idx;
    out_onehot[(size_t)row * NE + idx] = 1.0f;
    atomicAdd(&counts[idx], 1);
  }
  __syncthreads();
  for (int s = 128; s > 0; s >>= 1) {
    if (threadIdx.x < s) sred[threadIdx.x] += sred[threadIdx.x + s];
    __syncthreads();
  }
  if (threadIdx.x == 0) partials[blockIdx.x] = sred[0];
}

// ---------------------------------------------------------------------------
// k_final: loss = 1.25 * sum(partials) / (N*D); perplexity from counts.
// ---------------------------------------------------------------------------
__global__ __launch_bounds__(256) void k_final(
    const int* __restrict__ counts, const float* __restrict__ partials,
    float* __restrict__ out_loss, float* __restrict__ out_perp)
{
  __shared__ float sred[256];
  __shared__ float sl[256];
  float le = 0.0f;
  for (int e = threadIdx.x; e < NE; e += 256) {
    const float p = (float)counts[e] * (1.0f / 16384.0f);
    le += p * logf(p + 1e-10f);
  }
  float ll = 0.0f;
  for (int b = threadIdx.x; b < NROWS / 4; b += 256) ll += partials[b];
  sred[threadIdx.x] = le;
  sl[threadIdx.x] = ll;
  __syncthreads();
  for (int s = 128; s > 0; s >>= 1) {
    if (threadIdx.x < s) {
      sred[threadIdx.x] += sred[threadIdx.x + s];
      sl[threadIdx.x] += sl[threadIdx.x + s];
    }
    __syncthreads();
  }
  if (threadIdx.x == 0) {
    *out_perp = expf(-sred[0]);
    *out_loss = sl[0] * (1.25f / 4194304.0f);  // (1+beta) * sum / (N*D)
  }
}

// ---------------------------------------------------------------------------
// Output layout (float32, concatenated in reference return order):
//   [0]                loss                       (1)
//   [1 .. 4194304]     z_q_st                     (16384*256)
//   [4194305]          perplexity                 (1)
//   [4194306 ..]       min_encodings one-hot      (16384*8192)
//   [138412034 ..]     min_encoding_indices       (16384, written as float)
// ---------------------------------------------------------------------------
extern "C" void kernel_launch(void* const* d_in, const int* in_sizes, int n_in,
                              void* d_out, int out_size, void* d_ws, size_t ws_size,
                              hipStream_t stream) {
  const float* z   = (const float*)d_in[0];
  const float* emb = (const float*)d_in[1];

  float* out        = (float*)d_out;
  float* out_loss   = out;
  float* out_zq     = out + 1;
  float* out_perp   = out + 4194305;
  float* out_onehot = out + 4194306;
  float* out_idx    = out + 138412034;

  float* zsq      = (float*)d_ws;            // 16384 f
  float* esq      = zsq + NROWS;             // 8192 f
  u64*   best     = (u64*)(esq + NE);        // 16384 u64 (8B-aligned: offset 96 KB)
  int*   counts   = (int*)(best + NROWS);    // 8192 int
  float* partials = (float*)(counts + NE);   // 4096 f

  k_rowsq<<<96, 256, 0, stream>>>(z, emb, zsq, esq, best, counts);
  k_argmin<<<dim3(NROWS / TM, NCH), 256, 0, stream>>>(z, emb, zsq, esq, best,
                                                      out_onehot);
  k_gather2<<<NROWS / 4, 256, 0, stream>>>(z, emb, best, out_zq, out_onehot,
                                           out_idx, partials, counts);
  k_final<<<1, 256, 0, stream>>>(counts, partials, out_loss, out_perp);
}